// Round 3
// baseline (87.370 us; speedup 1.0000x reference)
//
#include <hip/hip_runtime.h>

// Problem constants (fixed by the reference): B=32, N=128, L=16, F=32, NAVG=50
#define BB 32
#define NN 128
#define LL 16
#define FF 32
constexpr float INV_NAVG = 1.0f / 50.0f;

// ---------------------------------------------------------------------------
// Kernel A: rowsum[b,i,l] = (1/NAVG) * sum_j inputs[b,i,j,l]
// 1024 blocks x 256 threads, 4 rows per block. float4 loads, fully coalesced.
// Thread t = jj*4 + c covers j in {jj, jj+64}, l-range 4c..4c+3.
// ---------------------------------------------------------------------------
__global__ __launch_bounds__(256) void k_rowsum(const float* __restrict__ in,
                                                float* __restrict__ rs) {
    __shared__ float4 red4[4][256];      // 16KB
    const int t = threadIdx.x;
    const int rowBase = blockIdx.x * 4;  // global row = b*128 + i

    const float4* in4 = reinterpret_cast<const float4*>(in);
#pragma unroll
    for (int r = 0; r < 4; ++r) {
        size_t base = (size_t)(rowBase + r) * (NN * LL / 4);   // 512 float4/row
        float4 u = in4[base + t];
        float4 v = in4[base + t + 256];
        float4 a;
        a.x = u.x + v.x; a.y = u.y + v.y; a.z = u.z + v.z; a.w = u.w + v.w;
        red4[r][t] = a;
    }
    __syncthreads();
#pragma unroll
    for (int s = 32; s >= 1; s >>= 1) {          // reduce jj: 64 -> 1
        if (t < s * 4) {
#pragma unroll
            for (int r = 0; r < 4; ++r) {
                float4 a = red4[r][t], c = red4[r][t + s * 4];
                a.x += c.x; a.y += c.y; a.z += c.z; a.w += c.w;
                red4[r][t] = a;
            }
        }
        __syncthreads();
    }
    if (t < 16) {
        int r = t >> 2, c = t & 3;
        float4 v = red4[r][c];
        v.x *= INV_NAVG; v.y *= INV_NAVG; v.z *= INV_NAVG; v.w *= INV_NAVG;
        reinterpret_cast<float4*>(rs)[(size_t)(rowBase + r) * 4 + c] = v;
    }
}

// ---------------------------------------------------------------------------
// Kernel B: everything else. 1024 blocks x 256 threads, 4 rows per block.
// Loads the batch's rowsum (8KB) into LDS, reduces totsum in-block
// (redundantly per block -- tiny), builds per-row f-vectors, then the main
// loop: out[b,i,j,f] = relu(in[b,i,j,:].w0 + a2[i] + rw3[j] + (i==j)*rwD[i]).
// ---------------------------------------------------------------------------
__global__ __launch_bounds__(256) void k_main(const float* __restrict__ in,
                                              const float* __restrict__ w,
                                              const float* __restrict__ bias,
                                              const float* __restrict__ dbias,
                                              const float* __restrict__ rs,
                                              float* __restrict__ out) {
    __shared__ float srs[NN * LL];       // 8KB  rowsum[b,:,:]
    __shared__ float redf[256];
    __shared__ float tot[LL];
    __shared__ float tbase[FF], ttd[FF];
    __shared__ float a2s[4][FF], rwDs[4][FF];

    const int t = threadIdx.x;
    const int rowBase = blockIdx.x * 4;
    const int b = rowBase >> 7;
    const int i0 = rowBase & 127;

    // stage rowsum[b,:,:]
    const float4* rs4 = reinterpret_cast<const float4*>(rs);
    float4* srs4 = reinterpret_cast<float4*>(srs);
    srs4[t]       = rs4[(size_t)b * 512 + t];
    srs4[t + 256] = rs4[(size_t)b * 512 + t + 256];
    __syncthreads();

    {   // totsum[l] = INV_NAVG * sum_i srs[i][l]
        int l = t & 15, g = t >> 4;
        float s = 0.f;
#pragma unroll
        for (int k = 0; k < 8; ++k) s += srs[(g + 16 * k) * LL + l];
        redf[t] = s;
        __syncthreads();
#pragma unroll
        for (int st = 8; st >= 1; st >>= 1) {
            if (t < st * 16) redf[t] += redf[t + st * 16];
            __syncthreads();
        }
        if (t < LL) tot[t] = redf[t] * INV_NAVG;
        __syncthreads();
    }

    if (t < FF) {   // tbase = totsum.w1 + bias ; ttd = totsum.w5 + diag_bias
        float bs = bias[t], td = dbias[t];
#pragma unroll
        for (int q = 0; q < LL; ++q) {
            float tv = tot[q];
            bs += tv * w[(q * 6 + 1) * FF + t];
            td += tv * w[(q * 6 + 5) * FF + t];
        }
        tbase[t] = bs; ttd[t] = td;
    }
    __syncthreads();

    if (t < 128) {  // a2s[r] = srs[i_r].w2 + tbase ; rwDs[r] = srs[i_r].w4 + ttd
        int r = t >> 5, f = t & 31;
        float s2 = 0.f, s4 = 0.f;
#pragma unroll
        for (int q = 0; q < LL; ++q) {
            float rv = srs[(i0 + r) * LL + q];
            s2 += rv * w[(q * 6 + 2) * FF + f];
            s4 += rv * w[(q * 6 + 4) * FF + f];
        }
        a2s[r][f] = s2 + tbase[f];
        rwDs[r][f] = s4 + ttd[f];
    }
    __syncthreads();

    // main loop
    const int f = t & 31, jg = t >> 5;   // 8 j-groups
    float w0r[LL], w3r[LL];
#pragma unroll
    for (int q = 0; q < LL; ++q) {
        w0r[q] = w[(q * 6 + 0) * FF + f];
        w3r[q] = w[(q * 6 + 3) * FF + f];
    }
    float a2v[4], rwDv[4];
#pragma unroll
    for (int r = 0; r < 4; ++r) { a2v[r] = a2s[r][f]; rwDv[r] = rwDs[r][f]; }

    float* outBase = out + (size_t)rowBase * NN * FF + f;

    for (int k = 0; k < 16; ++k) {
        int j = jg + 8 * k;
        const float* sj = &srs[j * LL];
        float rw3v = 0.f;
#pragma unroll
        for (int q = 0; q < LL; ++q) rw3v += sj[q] * w3r[q];   // LDS broadcast
#pragma unroll
        for (int r = 0; r < 4; ++r) {
            // input row re-read: uniform across the 32-lane f-group, L3-warm
            const float4* xr = reinterpret_cast<const float4*>(
                in + ((size_t)(rowBase + r) * NN + j) * LL);
            float4 x0 = xr[0], x1 = xr[1], x2 = xr[2], x3 = xr[3];
            float acc = a2v[r] + rw3v + ((j == i0 + r) ? rwDv[r] : 0.f);
            acc += x0.x * w0r[0] + x0.y * w0r[1] + x0.z * w0r[2] + x0.w * w0r[3];
            acc += x1.x * w0r[4] + x1.y * w0r[5] + x1.z * w0r[6] + x1.w * w0r[7];
            acc += x2.x * w0r[8] + x2.y * w0r[9] + x2.z * w0r[10] + x2.w * w0r[11];
            acc += x3.x * w0r[12] + x3.y * w0r[13] + x3.z * w0r[14] + x3.w * w0r[15];
            outBase[((size_t)r * NN + j) * FF] = fmaxf(acc, 0.f);
        }
    }
}

extern "C" void kernel_launch(void* const* d_in, const int* in_sizes, int n_in,
                              void* d_out, int out_size, void* d_ws, size_t ws_size,
                              hipStream_t stream) {
    const float* in    = (const float*)d_in[0];   // [B,N,N,L] fp32
    const float* w     = (const float*)d_in[1];   // [L,6,F]
    const float* bias  = (const float*)d_in[2];   // [F]
    const float* dbias = (const float*)d_in[3];   // [F]
    float* out = (float*)d_out;                   // [B,N,N,F] fp32
    float* rs  = (float*)d_ws;                    // B*N*L floats scratch

    k_rowsum<<<BB * NN / 4, 256, 0, stream>>>(in, rs);
    k_main  <<<BB * NN / 4, 256, 0, stream>>>(in, w, bias, dbias, rs, out);
}

// Round 4
// 41.381 us; speedup vs baseline: 2.1113x; 2.1113x over previous
//
#include <hip/hip_runtime.h>

// Problem constants (fixed by the reference): B=32, N=128, L=16, F=32, NAVG=50
#define BB 32
#define NN 128
#define LL 16
#define FF 32
constexpr float INV_NAVG = 1.0f / 50.0f;

// ---------------------------------------------------------------------------
// Kernel A: rowsum[b,i,l] = (1/NAVG) * sum_j inputs[b,i,j,l]   (4 rows/block)
// Also writes per-block partial totsum (sum of its 4 scaled rowsums) into a
// private slot tsp[b][slot][l] -- no atomics, no zeroing needed.
// ---------------------------------------------------------------------------
__global__ __launch_bounds__(256) void k_rowsum(const float* __restrict__ in,
                                                float* __restrict__ rs,
                                                float* __restrict__ tsp) {
    __shared__ float4 red4[4][256];      // 16KB
    const int t = threadIdx.x;
    const int blk = blockIdx.x;
    const int rowBase = blk * 4;         // global row = b*128 + i

    const float4* in4 = reinterpret_cast<const float4*>(in);
#pragma unroll
    for (int r = 0; r < 4; ++r) {
        size_t base = (size_t)(rowBase + r) * (NN * LL / 4);   // 512 float4/row
        float4 u = in4[base + t];
        float4 v = in4[base + t + 256];
        float4 a;
        a.x = u.x + v.x; a.y = u.y + v.y; a.z = u.z + v.z; a.w = u.w + v.w;
        red4[r][t] = a;
    }
    __syncthreads();
#pragma unroll
    for (int s = 32; s >= 1; s >>= 1) {          // reduce j-groups: 64 -> 1
        if (t < s * 4) {
#pragma unroll
            for (int r = 0; r < 4; ++r) {
                float4 a = red4[r][t], c = red4[r][t + s * 4];
                a.x += c.x; a.y += c.y; a.z += c.z; a.w += c.w;
                red4[r][t] = a;
            }
        }
        __syncthreads();
    }
    if (t < 16) {
        // scaled rowsum write (r = row, c = float4 chunk)
        int r = t >> 2, c = t & 3;
        float4 v = red4[r][c];
        v.x *= INV_NAVG; v.y *= INV_NAVG; v.z *= INV_NAVG; v.w *= INV_NAVG;
        reinterpret_cast<float4*>(rs)[(size_t)(rowBase + r) * 4 + c] = v;

        // partial totsum for l = t: sum over this block's 4 rows (scaled)
        int cc = t >> 2, comp = t & 3;
        float s = 0.f;
#pragma unroll
        for (int r2 = 0; r2 < 4; ++r2)
            s += reinterpret_cast<const float*>(&red4[r2][cc])[comp];
        tsp[(size_t)blk * LL + t] = s * INV_NAVG;   // slot = blk&31, b = blk>>5
    }
}

// ---------------------------------------------------------------------------
// Kernel P: per-batch finalize. 256 blocks (8 per b) x 256 threads.
//   tot[l]     = INV_NAVG * sum_slot tsp[b][slot][l]
//   rw3[b,j,f] = sum_l rowsum[b,j,l] * w[l,3,f]   (16 j's per block)
//   ts[b,l]    = tot[l]                            (written by grp 0 only)
// ---------------------------------------------------------------------------
__global__ __launch_bounds__(256) void k_pre(const float* __restrict__ rs,
                                             const float* __restrict__ tsp,
                                             const float* __restrict__ w,
                                             float* __restrict__ rw3,
                                             float* __restrict__ ts) {
    __shared__ float redf[256];
    __shared__ float tot[LL];
    __shared__ float rs16[256];          // 16 rows x 16 l
    const int t = threadIdx.x;
    const int b = blockIdx.x >> 3, grp = blockIdx.x & 7, i0 = grp * 16;

    // reduce 32 partial-totsum slots
    int l = t & 15, sg = t >> 4;         // 16 slot-groups x 2 slots
    redf[t] = tsp[(size_t)b * 32 * LL + sg * LL + l]
            + tsp[(size_t)b * 32 * LL + (sg + 16) * LL + l];
    __syncthreads();
#pragma unroll
    for (int st = 8; st >= 1; st >>= 1) {
        if (t < st * 16) redf[t] += redf[t + st * 16];
        __syncthreads();
    }
    if (t < LL) tot[t] = redf[t] * INV_NAVG;
    rs16[t] = rs[((size_t)b * NN + i0) * LL + t];
    __syncthreads();

#pragma unroll
    for (int k = 0; k < 2; ++k) {
        int idx = t + 256 * k;
        int il = idx >> 5, f = idx & 31;
        float v = 0.f;
#pragma unroll
        for (int q = 0; q < LL; ++q)
            v += rs16[il * LL + q] * w[(q * 6 + 3) * FF + f];
        rw3[((size_t)b * NN + i0 + il) * FF + f] = v;
    }
    if (grp == 0 && t < LL) ts[b * LL + t] = tot[t];
}

// ---------------------------------------------------------------------------
// Kernel M: main. 2048 blocks (one (b,i) row each) x 256 threads.
// Stage input row in LDS; a2s/rwDs computed once per block by lanes t<32;
// hot loop touches only LDS + one coalesced rw3 load + one dword store.
// ---------------------------------------------------------------------------
__global__ __launch_bounds__(256) void k_main(const float* __restrict__ in,
                                              const float* __restrict__ w,
                                              const float* __restrict__ bias,
                                              const float* __restrict__ dbias,
                                              const float* __restrict__ rs,
                                              const float* __restrict__ ts,
                                              const float* __restrict__ rw3,
                                              float* __restrict__ out) {
    __shared__ float inRow[NN * LL];     // 8KB
    __shared__ float a2s[FF], rwDs[FF];
    const int t = threadIdx.x;
    const int blk = blockIdx.x;          // b*N + i
    const int b = blk >> 7, i = blk & 127;

    const float4* src4 = reinterpret_cast<const float4*>(in + (size_t)blk * (NN * LL));
    float4* dst4 = reinterpret_cast<float4*>(inRow);
    dst4[t] = src4[t];
    dst4[t + 256] = src4[t + 256];

    if (t < FF) {    // a2s[f] = rs_i.w2 + tot.w1 + bias ; rwDs[f] = rs_i.w4 + tot.w5 + dbias
        float a = bias[t], d = dbias[t];
#pragma unroll
        for (int q = 0; q < LL; ++q) {
            float rv = rs[(size_t)blk * LL + q];   // uniform -> s_load
            float tv = ts[b * LL + q];             // uniform -> s_load
            a += rv * w[(q * 6 + 2) * FF + t] + tv * w[(q * 6 + 1) * FF + t];
            d += rv * w[(q * 6 + 4) * FF + t] + tv * w[(q * 6 + 5) * FF + t];
        }
        a2s[t] = a; rwDs[t] = d;
    }
    __syncthreads();

    const int f = t & 31, jg = t >> 5;   // 8 j-groups
    float w0r[LL];
#pragma unroll
    for (int q = 0; q < LL; ++q) w0r[q] = w[q * 6 * FF + f];
    const float a2v = a2s[f], rwDv = rwDs[f];
    const float* rw3b = rw3 + (size_t)b * NN * FF + f;
    float* outb = out + (size_t)blk * NN * FF + f;

#pragma unroll 4
    for (int k = 0; k < 16; ++k) {
        int j = jg + 8 * k;
        float acc = a2v + rw3b[(size_t)j * FF] + ((j == i) ? rwDv : 0.f);
        const float4* xr = reinterpret_cast<const float4*>(&inRow[j * LL]);
        float4 x0 = xr[0], x1 = xr[1], x2 = xr[2], x3 = xr[3];
        acc += x0.x * w0r[0] + x0.y * w0r[1] + x0.z * w0r[2] + x0.w * w0r[3];
        acc += x1.x * w0r[4] + x1.y * w0r[5] + x1.z * w0r[6] + x1.w * w0r[7];
        acc += x2.x * w0r[8] + x2.y * w0r[9] + x2.z * w0r[10] + x2.w * w0r[11];
        acc += x3.x * w0r[12] + x3.y * w0r[13] + x3.z * w0r[14] + x3.w * w0r[15];
        outb[(size_t)j * FF] = fmaxf(acc, 0.f);
    }
}

extern "C" void kernel_launch(void* const* d_in, const int* in_sizes, int n_in,
                              void* d_out, int out_size, void* d_ws, size_t ws_size,
                              hipStream_t stream) {
    const float* in    = (const float*)d_in[0];   // [B,N,N,L] fp32
    const float* w     = (const float*)d_in[1];   // [L,6,F]
    const float* bias  = (const float*)d_in[2];   // [F]
    const float* dbias = (const float*)d_in[3];   // [F]
    float* out = (float*)d_out;                   // [B,N,N,F] fp32
    float* ws  = (float*)d_ws;

    float* rs  = ws;                                   // B*N*L   = 65536 floats
    float* tsp = rs  + (size_t)BB * NN * LL;           // B*32*L  = 16384
    float* ts  = tsp + (size_t)BB * 32 * LL;           // B*L     = 512
    float* rw3 = ts  + (size_t)BB * LL;                // B*N*F   = 131072

    k_rowsum<<<BB * NN / 4, 256, 0, stream>>>(in, rs, tsp);
    k_pre   <<<BB * 8,      256, 0, stream>>>(rs, tsp, w, rw3, ts);
    k_main  <<<BB * NN,     256, 0, stream>>>(in, w, bias, dbias, rs, ts, rw3, out);
}